// Round 2
// baseline (1258.871 us; speedup 1.0000x reference)
//
#include <hip/hip_runtime.h>
#include <stdint.h>

typedef __attribute__((ext_vector_type(8))) short bf16x8;
typedef __attribute__((ext_vector_type(4))) short s16x4;
typedef __attribute__((ext_vector_type(4))) float f32x4;

__device__ __forceinline__ short f2bf(float f){
  unsigned x = __float_as_uint(f);
  unsigned r = (x + 0x7fffu + ((x >> 16) & 1u)) >> 16;
  return (short)r;
}

// async global->LDS, 16B per lane (dest must be wave-uniform base + lane*16)
__device__ __forceinline__ void g2l16(const void* g, void* l){
  __builtin_amdgcn_global_load_lds(
      (const __attribute__((address_space(1))) unsigned int*)(unsigned long long)(uintptr_t)g,
      (__attribute__((address_space(3))) unsigned int*)(unsigned int)(uintptr_t)l,
      16, 0, 0);
}

// ---------------------------------------------------------------------------
// f32 -> bf16 convert, 8 elems/thread
// ---------------------------------------------------------------------------
__global__ __launch_bounds__(256) void cvt_bf16(const float* __restrict__ in,
                                                short* __restrict__ out, int n8){
  const int i = blockIdx.x * 256 + threadIdx.x;
  if (i >= n8) return;
  const float4* p = (const float4*)in + (size_t)i * 2;
  const float4 a = p[0], b = p[1];
  bf16x8 v;
  v[0] = f2bf(a.x); v[1] = f2bf(a.y); v[2] = f2bf(a.z); v[3] = f2bf(a.w);
  v[4] = f2bf(b.x); v[5] = f2bf(b.y); v[6] = f2bf(b.z); v[7] = f2bf(b.w);
  *(bf16x8*)(out + (size_t)i * 8) = v;
}

// ---------------------------------------------------------------------------
// Pack W (f32, 1024x1024 row-major K x N) into bf16 tiles:
// packed[(nt*32+kt)*4096 + nl*32 + kl] = W[(kt*32+kl)*1024 + nt*128 + nl]
// ---------------------------------------------------------------------------
__global__ __launch_bounds__(256) void pack_w(const float* __restrict__ W,
                                              short* __restrict__ out){
  const int tile = blockIdx.x;           // 0..255
  const int kt = tile & 31, nt = tile >> 5;
  const int t = threadIdx.x;
  short* o = out + (size_t)tile * 4096;
  #pragma unroll
  for (int i = 0; i < 16; ++i){
    int flat = i * 256 + t;              // 0..4095
    int kl = flat >> 7;                  // /128
    int nl = flat & 127;
    o[nl * 32 + kl] = f2bf(W[(size_t)(kt * 32 + kl) * 1024 + nt * 128 + nl]);
  }
}

// ---------------------------------------------------------------------------
// GEMM: C(M,1024) = A(M,1024)bf16 @ Wp + bias(f32).  128x128 tile, BK=32.
// OM=0: C bf16 row-major. OM=1: C bf16 as (B,H=16,DK=64,S). OM=2: C f32 row-major.
// ---------------------------------------------------------------------------
template<int OM>
__global__ __launch_bounds__(256)
void gemm128(const short* __restrict__ A, const short* __restrict__ Wp,
             const float* __restrict__ bias, void* __restrict__ Cv, int S){
  __shared__ short sA[128 * 32];
  __shared__ short sB[128 * 32];
  const int t = threadIdx.x;
  const int m0 = blockIdx.x * 128;
  const int nt = blockIdx.y;             // 0..7
  const int n0 = nt * 128;
  const int w = t >> 6, lane = t & 63, lr = lane & 15, lg = lane >> 4;
  const int wm = (w >> 1) * 64, wn = (w & 1) * 64;

  const int arow  = t >> 2;
  const int acol8 = (t & 3) * 8;
  const short* Ag = A + (size_t)(m0 + arow) * 1024 + acol8;
  const short* Bg = Wp + (size_t)nt * 32 * 4096 + t * 8;
  short* sAp = sA + t * 8;
  short* sBp = sB + t * 8;

  f32x4 acc[4][4] = {};

  for (int kt = 0; kt < 32; ++kt){
    __syncthreads();
    g2l16(Ag + kt * 32, sAp);
    g2l16(Ag + 64 * 1024 + kt * 32, sAp + 64 * 32);
    const short* bt = Bg + (size_t)kt * 4096;
    g2l16(bt, sBp);
    g2l16(bt + 2048, sBp + 2048);
    __syncthreads();

    bf16x8 af[4], bfr[4];
    #pragma unroll
    for (int mi = 0; mi < 4; ++mi)
      af[mi] = *(const bf16x8*)&sA[(wm + mi * 16 + lr) * 32 + lg * 8];
    #pragma unroll
    for (int ni = 0; ni < 4; ++ni)
      bfr[ni] = *(const bf16x8*)&sB[(wn + ni * 16 + lr) * 32 + lg * 8];
    #pragma unroll
    for (int mi = 0; mi < 4; ++mi)
      #pragma unroll
      for (int ni = 0; ni < 4; ++ni)
        acc[mi][ni] = __builtin_amdgcn_mfma_f32_16x16x32_bf16(
            af[mi], bfr[ni], acc[mi][ni], 0, 0, 0);
  }

  #pragma unroll
  for (int ni = 0; ni < 4; ++ni){
    const int n = n0 + wn + ni * 16 + lr;
    const float bv = bias[n];
    #pragma unroll
    for (int mi = 0; mi < 4; ++mi){
      const int mb = m0 + wm + mi * 16 + lg * 4;
      if (OM == 0){
        short* C = (short*)Cv;
        #pragma unroll
        for (int j = 0; j < 4; ++j)
          C[(size_t)(mb + j) * 1024 + n] = f2bf(acc[mi][ni][j] + bv);
      } else if (OM == 1){
        short* C = (short*)Cv;
        const int bb = mb / S, sb = mb % S;
        const int hh = n >> 6, dk = n & 63;
        s16x4 pk;
        #pragma unroll
        for (int j = 0; j < 4; ++j) pk[j] = f2bf(acc[mi][ni][j] + bv);
        *(s16x4*)&C[(((size_t)bb * 16 + hh) * 64 + dk) * S + sb] = pk;
      } else {
        float* C = (float*)Cv;
        #pragma unroll
        for (int j = 0; j < 4; ++j)
          C[(size_t)(mb + j) * 1024 + n] = acc[mi][ni][j] + bv;
      }
    }
  }
}

// ---------------------------------------------------------------------------
// Fused attention for one modality. Block = (b, h, 32 q-rows), 4 waves.
// MODE: 0 scores = o ; 1 scores += 0.5*o ; 2 concat = bf16(scores + 0.5*o)
// aw (f32) written for MODE 0/1.
// ---------------------------------------------------------------------------
template<int SK, bool HAS_MASK, int MODE>
__global__ __launch_bounds__(256)
void attn_kernel(const short* __restrict__ Qp, const short* __restrict__ Kp,
                 const short* __restrict__ Vt,
                 const int* __restrict__ mask, const int* __restrict__ pad,
                 float* __restrict__ aw, float* __restrict__ scores,
                 short* __restrict__ concat){
  constexpr int SW   = SK / 4;     // per-wave slice
  constexpr int NSI  = SW / 16;    // s-fragments per wave
  constexpr int NKT  = SW / 32;    // PV k-steps
  constexpr int WSTR = SK + 8;     // padded LDS row stride (elems)

  __shared__ short w16[32 * WSTR];
  __shared__ float red[32][4];
  __shared__ float Obuf[32][64];

  const int bid = blockIdx.x;
  const int qt = bid & 15, h = (bid >> 4) & 15, b = bid >> 8;
  const int q0 = qt * 32;
  const int t = threadIdx.x, w = t >> 6, lane = t & 63, lr = lane & 15, lg = lane >> 4;
  const int s0 = w * SW;

  for (int i = t; i < 32 * 64; i += 256) ((float*)Obuf)[i] = 0.f;

  // Q fragments (2 qi x 2 dk-halves)
  const short* Qb = Qp + (size_t)(b * 512 + q0) * 1024 + h * 64;
  bf16x8 qf[2][2];
  #pragma unroll
  for (int qi = 0; qi < 2; ++qi)
    #pragma unroll
    for (int dt = 0; dt < 2; ++dt)
      qf[qi][dt] = *(const bf16x8*)&Qb[(qi * 16 + lr) * 1024 + dt * 32 + lg * 8];

  // S = Q K^T
  const short* Kb = Kp + ((size_t)b * SK + s0) * 1024 + h * 64;
  f32x4 accs[2][NSI] = {};
  #pragma unroll
  for (int si = 0; si < NSI; ++si){
    #pragma unroll
    for (int dt = 0; dt < 2; ++dt){
      bf16x8 kf = *(const bf16x8*)&Kb[(si * 16 + lr) * 1024 + dt * 32 + lg * 8];
      accs[0][si] = __builtin_amdgcn_mfma_f32_16x16x32_bf16(qf[0][dt], kf, accs[0][si], 0, 0, 0);
      accs[1][si] = __builtin_amdgcn_mfma_f32_16x16x32_bf16(qf[1][dt], kf, accs[1][si], 0, 0, 0);
    }
  }

  // scale + mask
  #pragma unroll
  for (int qi = 0; qi < 2; ++qi)
    #pragma unroll
    for (int si = 0; si < NSI; ++si)
      #pragma unroll
      for (int j = 0; j < 4; ++j){
        float v = accs[qi][si][j] * 0.125f;
        if (HAS_MASK){
          const int qg = q0 + qi * 16 + lg * 4 + j;
          const int s  = s0 + si * 16 + lr;
          if (mask[((size_t)b * 512 + qg) * SK + s] != 0 ||
              pad[(size_t)b * SK + s] != 0) v = -1e30f;
        }
        accs[qi][si][j] = v;
      }

  // row max (16-lane butterfly, then cross-wave via LDS)
  float rmax[2][4];
  #pragma unroll
  for (int qi = 0; qi < 2; ++qi)
    #pragma unroll
    for (int j = 0; j < 4; ++j){
      float m = -3.4e38f;
      #pragma unroll
      for (int si = 0; si < NSI; ++si) m = fmaxf(m, accs[qi][si][j]);
      #pragma unroll
      for (int d = 1; d < 16; d <<= 1) m = fmaxf(m, __shfl_xor(m, d));
      rmax[qi][j] = m;
    }
  if (lr == 0){
    #pragma unroll
    for (int qi = 0; qi < 2; ++qi)
      #pragma unroll
      for (int j = 0; j < 4; ++j) red[qi * 16 + lg * 4 + j][w] = rmax[qi][j];
  }
  __syncthreads();
  #pragma unroll
  for (int qi = 0; qi < 2; ++qi)
    #pragma unroll
    for (int j = 0; j < 4; ++j){
      const int r = qi * 16 + lg * 4 + j;
      rmax[qi][j] = fmaxf(fmaxf(red[r][0], red[r][1]), fmaxf(red[r][2], red[r][3]));
    }
  __syncthreads();

  // exp + row sum
  float rinv[2][4];
  #pragma unroll
  for (int qi = 0; qi < 2; ++qi)
    #pragma unroll
    for (int j = 0; j < 4; ++j){
      float ssum = 0.f;
      #pragma unroll
      for (int si = 0; si < NSI; ++si){
        float e = __expf(accs[qi][si][j] - rmax[qi][j]);
        accs[qi][si][j] = e;
        ssum += e;
      }
      #pragma unroll
      for (int d = 1; d < 16; d <<= 1) ssum += __shfl_xor(ssum, d);
      rinv[qi][j] = ssum;
    }
  if (lr == 0){
    #pragma unroll
    for (int qi = 0; qi < 2; ++qi)
      #pragma unroll
      for (int j = 0; j < 4; ++j) red[qi * 16 + lg * 4 + j][w] = rinv[qi][j];
  }
  __syncthreads();
  #pragma unroll
  for (int qi = 0; qi < 2; ++qi)
    #pragma unroll
    for (int j = 0; j < 4; ++j){
      const int r = qi * 16 + lg * 4 + j;
      rinv[qi][j] = 1.0f / (red[r][0] + red[r][1] + red[r][2] + red[r][3]);
    }

  // normalize; write w to LDS (+ aw f32 to global for e/i)
  #pragma unroll
  for (int qi = 0; qi < 2; ++qi)
    #pragma unroll
    for (int si = 0; si < NSI; ++si)
      #pragma unroll
      for (int j = 0; j < 4; ++j){
        const float wv = accs[qi][si][j] * rinv[qi][j];
        const int qq = qi * 16 + lg * 4 + j;
        const int s  = s0 + si * 16 + lr;
        w16[qq * WSTR + s] = f2bf(wv);
        if (MODE != 2)
          aw[(((size_t)b * 16 + h) * 512 + q0 + qq) * SK + s] = wv;
      }

  // PV over own slice (same-wave LDS write->read; DS ops are in-order)
  f32x4 acco[2][4] = {};
  const short* Vb = Vt + ((size_t)b * 16 + h) * 64 * SK;
  #pragma unroll
  for (int kt = 0; kt < NKT; ++kt){
    const int ks = s0 + kt * 32;
    bf16x8 vf[4];
    #pragma unroll
    for (int ni = 0; ni < 4; ++ni)
      vf[ni] = *(const bf16x8*)&Vb[(ni * 16 + lr) * SK + ks + lg * 8];
    #pragma unroll
    for (int qi = 0; qi < 2; ++qi){
      bf16x8 wf = *(const bf16x8*)&w16[(qi * 16 + lr) * WSTR + ks + lg * 8];
      #pragma unroll
      for (int ni = 0; ni < 4; ++ni)
        acco[qi][ni] = __builtin_amdgcn_mfma_f32_16x16x32_bf16(wf, vf[ni], acco[qi][ni], 0, 0, 0);
    }
  }

  // deterministic cross-wave reduce
  __syncthreads();
  for (int ww = 0; ww < 4; ++ww){
    if (w == ww){
      #pragma unroll
      for (int qi = 0; qi < 2; ++qi)
        #pragma unroll
        for (int ni = 0; ni < 4; ++ni)
          #pragma unroll
          for (int j = 0; j < 4; ++j)
            Obuf[qi * 16 + lg * 4 + j][ni * 16 + lr] += acco[qi][ni][j];
    }
    __syncthreads();
  }

  // combine with running scores
  const int qq = t >> 3;
  const int d0 = (t & 7) * 8;
  const size_t base = ((size_t)(b * 512 + q0 + qq)) * 1024 + h * 64 + d0;
  #pragma unroll
  for (int i = 0; i < 8; ++i){
    const float v = Obuf[qq][d0 + i];
    if (MODE == 0)      scores[base + i] = v;
    else if (MODE == 1) scores[base + i] += 0.5f * v;
    else                concat[base + i] = f2bf(scores[base + i] + 0.5f * v);
  }
}

// ---------------------------------------------------------------------------
extern "C" void kernel_launch(void* const* d_in, const int* in_sizes, int n_in,
                              void* d_out, int out_size, void* d_ws, size_t ws_size,
                              hipStream_t stream){
  const float* q    = (const float*)d_in[0];
  const float* k_e  = (const float*)d_in[1];
  const float* v_e  = (const float*)d_in[2];
  const float* k_i  = (const float*)d_in[3];
  const float* v_i  = (const float*)d_in[4];
  const float* k_ei = (const float*)d_in[5];
  const float* v_ei = (const float*)d_in[6];
  const int* mask_e  = (const int*)d_in[7];
  const int* mask_ei = (const int*)d_in[8];
  const int* pad_e   = (const int*)d_in[9];
  const int* pad_ei  = (const int*)d_in[10];
  const float* Wq   = (const float*)d_in[11]; const float* bq   = (const float*)d_in[12];
  const float* Wke  = (const float*)d_in[13]; const float* bke  = (const float*)d_in[14];
  const float* Wve  = (const float*)d_in[15]; const float* bve  = (const float*)d_in[16];
  const float* Wki  = (const float*)d_in[17]; const float* bki  = (const float*)d_in[18];
  const float* Wvi  = (const float*)d_in[19]; const float* bvi  = (const float*)d_in[20];
  const float* Wkei = (const float*)d_in[21]; const float* bkei = (const float*)d_in[22];
  const float* Wvei = (const float*)d_in[23]; const float* bvei = (const float*)d_in[24];
  const float* Wout = (const float*)d_in[25]; const float* bout = (const float*)d_in[26];

  char* ws = (char*)d_ws;
  short* PW     = (short*)(ws);                 // 16 MB: 8 packed weights (bf16)
  short* Abf    = (short*)(ws + 16777216);      // 24 MB: reused bf16 activation staging
  short* Qp     = (short*)(ws + 41943040);      // 8192x1024 bf16
  short* Kep    = (short*)(ws + 58720256);      // 8192x1024 bf16
  short* Kip    = (short*)(ws + 75497472);      // 4096x1024 bf16
  short* Keip   = (short*)(ws + 83886080);      // 12288x1024 bf16
  short* Vte    = (short*)(ws + 109051904);     // (16,16,64,512) bf16
  short* Vti    = (short*)(ws + 125829120);     // (16,16,64,256) bf16
  short* Vtei   = (short*)(ws + 134217728);     // (16,16,64,768) bf16
  float* scores = (float*)(ws + 159383552);     // 8192x1024 f32
  short* concat = (short*)(ws + 192937984);     // 8192x1024 bf16  (ends 209715200)

  float* out0 = (float*)d_out;
  float* aw_e = out0 + 8388608;
  float* aw_i = out0 + 75497472;

  const float* Wl[8] = {Wq, Wke, Wve, Wki, Wvi, Wkei, Wvei, Wout};
  for (int m = 0; m < 8; ++m)
    pack_w<<<256, 256, 0, stream>>>(Wl[m], PW + (size_t)m * 1048576);

  struct Proj { const float* x; int n8; int blocks; int grid; const float* bias; int om; void* out; int S; int widx; };
  // q
  cvt_bf16<<<4096, 256, 0, stream>>>(q, Abf, 1048576);
  gemm128<0><<<dim3(64, 8), 256, 0, stream>>>(Abf, PW + 0 * 1048576, bq, Qp, 512);
  // k_e
  cvt_bf16<<<4096, 256, 0, stream>>>(k_e, Abf, 1048576);
  gemm128<0><<<dim3(64, 8), 256, 0, stream>>>(Abf, PW + 1 * 1048576, bke, Kep, 512);
  // v_e
  cvt_bf16<<<4096, 256, 0, stream>>>(v_e, Abf, 1048576);
  gemm128<1><<<dim3(64, 8), 256, 0, stream>>>(Abf, PW + 2 * 1048576, bve, Vte, 512);
  // k_i
  cvt_bf16<<<2048, 256, 0, stream>>>(k_i, Abf, 524288);
  gemm128<0><<<dim3(32, 8), 256, 0, stream>>>(Abf, PW + 3 * 1048576, bki, Kip, 256);
  // v_i
  cvt_bf16<<<2048, 256, 0, stream>>>(v_i, Abf, 524288);
  gemm128<1><<<dim3(32, 8), 256, 0, stream>>>(Abf, PW + 4 * 1048576, bvi, Vti, 256);
  // k_ei
  cvt_bf16<<<6144, 256, 0, stream>>>(k_ei, Abf, 1572864);
  gemm128<0><<<dim3(96, 8), 256, 0, stream>>>(Abf, PW + 5 * 1048576, bkei, Keip, 768);
  // v_ei
  cvt_bf16<<<6144, 256, 0, stream>>>(v_ei, Abf, 1572864);
  gemm128<1><<<dim3(96, 8), 256, 0, stream>>>(Abf, PW + 6 * 1048576, bvei, Vtei, 768);

  attn_kernel<512, true , 0><<<4096, 256, 0, stream>>>(Qp, Kep,  Vte,  mask_e,  pad_e,   aw_e, scores, nullptr);
  attn_kernel<256, false, 1><<<4096, 256, 0, stream>>>(Qp, Kip,  Vti,  nullptr, nullptr, aw_i, scores, nullptr);
  attn_kernel<768, true , 2><<<4096, 256, 0, stream>>>(Qp, Keip, Vtei, mask_ei, pad_ei,  nullptr, scores, concat);

  gemm128<2><<<dim3(64, 8), 256, 0, stream>>>(concat, PW + 7 * 1048576, bout, out0, 512);
}

// Round 3
// 747.824 us; speedup vs baseline: 1.6834x; 1.6834x over previous
//
#include <hip/hip_runtime.h>
#include <stdint.h>

typedef __attribute__((ext_vector_type(8))) short bf16x8;
typedef __attribute__((ext_vector_type(4))) short s16x4;
typedef __attribute__((ext_vector_type(4))) float f32x4;

__device__ __forceinline__ short f2bf(float f){
  unsigned x = __float_as_uint(f);
  unsigned r = (x + 0x7fffu + ((x >> 16) & 1u)) >> 16;
  return (short)r;
}

// async global->LDS, 16B per lane (dest must be wave-uniform base + lane*16)
__device__ __forceinline__ void g2l16(const void* g, void* l){
  __builtin_amdgcn_global_load_lds(
      (const __attribute__((address_space(1))) unsigned int*)(unsigned long long)(uintptr_t)g,
      (__attribute__((address_space(3))) unsigned int*)(unsigned int)(uintptr_t)l,
      16, 0, 0);
}

// ---------------------------------------------------------------------------
// f32 -> bf16 convert, 8 elems/thread
// ---------------------------------------------------------------------------
__global__ __launch_bounds__(256) void cvt_bf16(const float* __restrict__ in,
                                                short* __restrict__ out, int n8){
  const int i = blockIdx.x * 256 + threadIdx.x;
  if (i >= n8) return;
  const float4* p = (const float4*)in + (size_t)i * 2;
  const float4 a = p[0], b = p[1];
  bf16x8 v;
  v[0] = f2bf(a.x); v[1] = f2bf(a.y); v[2] = f2bf(a.z); v[3] = f2bf(a.w);
  v[4] = f2bf(b.x); v[5] = f2bf(b.y); v[6] = f2bf(b.z); v[7] = f2bf(b.w);
  *(bf16x8*)(out + (size_t)i * 8) = v;
}

// ---------------------------------------------------------------------------
// (mask || pad) -> bitmask. grid: (SK/256, B*SQ). 1 bit per (row, s).
// ---------------------------------------------------------------------------
__global__ __launch_bounds__(256)
void make_bits(const int* __restrict__ mask, const int* __restrict__ pad,
               unsigned* __restrict__ bits, int SK){
  const int s = blockIdx.x * 256 + threadIdx.x;
  const size_t row = blockIdx.y;               // b*512 + q
  const int b = (int)(row >> 9);
  const bool v = (mask[row * SK + s] != 0) || (pad[(size_t)b * SK + s] != 0);
  unsigned long long bal = __ballot(v);
  const int lane = threadIdx.x & 63;
  if ((lane & 31) == 0)
    bits[(row * SK + s) >> 5] = (unsigned)(bal >> (lane & 32));
}

// ---------------------------------------------------------------------------
// Pack W (f32, 1024x1024 row-major K x N) into bf16 tiles:
// packed[(nt*32+kt)*4096 + nl*32 + kl] = W[(kt*32+kl)*1024 + nt*128 + nl]
// ---------------------------------------------------------------------------
__global__ __launch_bounds__(256) void pack_w(const float* __restrict__ W,
                                              short* __restrict__ out){
  const int tile = blockIdx.x;           // 0..255
  const int kt = tile & 31, nt = tile >> 5;
  const int t = threadIdx.x;
  short* o = out + (size_t)tile * 4096;
  #pragma unroll
  for (int i = 0; i < 16; ++i){
    int flat = i * 256 + t;              // 0..4095
    int kl = flat >> 7;                  // /128
    int nl = flat & 127;
    o[nl * 32 + kl] = f2bf(W[(size_t)(kt * 32 + kl) * 1024 + nt * 128 + nl]);
  }
}

// ---------------------------------------------------------------------------
// GEMM: C(M,1024) = A(M,1024)bf16 @ Wp + bias(f32).  128x128 tile, BK=32.
// OM=0: C bf16 row-major. OM=1: C bf16 as (B,H=16,DK=64,S). OM=2: C f32 row-major.
// ---------------------------------------------------------------------------
template<int OM>
__global__ __launch_bounds__(256)
void gemm128(const short* __restrict__ A, const short* __restrict__ Wp,
             const float* __restrict__ bias, void* __restrict__ Cv, int S){
  __shared__ short sA[128 * 32];
  __shared__ short sB[128 * 32];
  const int t = threadIdx.x;
  const int m0 = blockIdx.x * 128;
  const int nt = blockIdx.y;             // 0..7
  const int n0 = nt * 128;
  const int w = t >> 6, lane = t & 63, lr = lane & 15, lg = lane >> 4;
  const int wm = (w >> 1) * 64, wn = (w & 1) * 64;

  const int arow  = t >> 2;
  const int acol8 = (t & 3) * 8;
  const short* Ag = A + (size_t)(m0 + arow) * 1024 + acol8;
  const short* Bg = Wp + (size_t)nt * 32 * 4096 + t * 8;
  short* sAp = sA + t * 8;
  short* sBp = sB + t * 8;

  f32x4 acc[4][4] = {};

  for (int kt = 0; kt < 32; ++kt){
    __syncthreads();
    g2l16(Ag + kt * 32, sAp);
    g2l16(Ag + 64 * 1024 + kt * 32, sAp + 64 * 32);
    const short* bt = Bg + (size_t)kt * 4096;
    g2l16(bt, sBp);
    g2l16(bt + 2048, sBp + 2048);
    __syncthreads();

    bf16x8 af[4], bfr[4];
    #pragma unroll
    for (int mi = 0; mi < 4; ++mi)
      af[mi] = *(const bf16x8*)&sA[(wm + mi * 16 + lr) * 32 + lg * 8];
    #pragma unroll
    for (int ni = 0; ni < 4; ++ni)
      bfr[ni] = *(const bf16x8*)&sB[(wn + ni * 16 + lr) * 32 + lg * 8];
    #pragma unroll
    for (int mi = 0; mi < 4; ++mi)
      #pragma unroll
      for (int ni = 0; ni < 4; ++ni)
        acc[mi][ni] = __builtin_amdgcn_mfma_f32_16x16x32_bf16(
            af[mi], bfr[ni], acc[mi][ni], 0, 0, 0);
  }

  #pragma unroll
  for (int ni = 0; ni < 4; ++ni){
    const int n = n0 + wn + ni * 16 + lr;
    const float bv = bias[n];
    #pragma unroll
    for (int mi = 0; mi < 4; ++mi){
      const int mb = m0 + wm + mi * 16 + lg * 4;
      if (OM == 0){
        short* C = (short*)Cv;
        #pragma unroll
        for (int j = 0; j < 4; ++j)
          C[(size_t)(mb + j) * 1024 + n] = f2bf(acc[mi][ni][j] + bv);
      } else if (OM == 1){
        short* C = (short*)Cv;
        const int bb = mb / S, sb = mb % S;
        const int hh = n >> 6, dk = n & 63;
        s16x4 pk;
        #pragma unroll
        for (int j = 0; j < 4; ++j) pk[j] = f2bf(acc[mi][ni][j] + bv);
        *(s16x4*)&C[(((size_t)bb * 16 + hh) * 64 + dk) * S + sb] = pk;
      } else {
        float* C = (float*)Cv;
        #pragma unroll
        for (int j = 0; j < 4; ++j)
          C[(size_t)(mb + j) * 1024 + n] = acc[mi][ni][j] + bv;
      }
    }
  }
}

// ---------------------------------------------------------------------------
// Two-phase flash attention. Block = (b, h, 64 q-rows), 4 waves (16 q each).
// Phase 1: per s-tile(128) stage K -> QK^T -> online (m,l) per lane.
// Phase 2: re-stage K+V -> QK^T -> P=exp(s-m)/l -> aw + P(LDS) -> PV.
// MODE: 0 scores = o ; 1 scores += 0.5*o ; 2 concat = bf16(scores + 0.5*o)
// ---------------------------------------------------------------------------
template<int SK, bool HAS_BIAS, int MODE>
__global__ __launch_bounds__(256)
void attn2(const short* __restrict__ Qp, const short* __restrict__ Kp,
           const short* __restrict__ Vt, const unsigned* __restrict__ bits,
           float* __restrict__ aw, float* __restrict__ scores,
           short* __restrict__ concat){
  constexpr int NT  = SK / 128;
  constexpr int SKW = SK / 32;
  __shared__ short sK[8192];   // [128 s][64 d], chunk16 ^= (s&7)
  __shared__ short sV[8192];   // [64 d][128 s], chunk16 ^= (d&15)
  __shared__ short sP[8192];   // per-wave [16 q][128 s], chunk16 ^= q

  const int bid = blockIdx.x;
  const int qt = bid & 7, h = (bid >> 3) & 15, b = bid >> 7;
  const int q0 = qt * 64;
  const int t = threadIdx.x, w = t >> 6, lane = t & 63;
  const int lr = lane & 15, lg = lane >> 4;
  const int qw = q0 + w * 16;

  // Q fragments (A-layout: row=lr, k=d)
  const short* Qb = Qp + ((size_t)(b * 512 + qw + lr)) * 1024 + h * 64;
  bf16x8 qf[2];
  qf[0] = *(const bf16x8*)&Qb[lg * 8];
  qf[1] = *(const bf16x8*)&Qb[32 + lg * 8];

  // staging pointers
  const int kchunk = (lane & 7) ^ ((lane >> 3) & 7);
  const short* Ksrc = Kp + ((size_t)b * SK + w * 32 + (lane >> 3)) * 1024 + h * 64 + kchunk * 8;
  short* sKd = sK + w * 2048 + lane * 8;
  short* sVd = sV + w * 2048 + lane * 8;
  const short* Vsrc = Vt + ((size_t)(b * 16 + h)) * 64 * SK;
  short* sPw = sP + w * 2048;

  const unsigned* bitrow[4];
  if (HAS_BIAS){
    #pragma unroll
    for (int j = 0; j < 4; ++j)
      bitrow[j] = bits + ((size_t)(b * 512 + qw + lg * 4 + j)) * SKW;
  }

  float mrow[4], lrow[4];
  #pragma unroll
  for (int j = 0; j < 4; ++j){ mrow[j] = -3.4e38f; lrow[j] = 0.f; }

  // ---------------- Phase 1: stats ----------------
  for (int tt = 0; tt < NT; ++tt){
    const int s0 = tt * 128;
    __syncthreads();
    #pragma unroll
    for (int i = 0; i < 4; ++i)
      g2l16(Ksrc + ((size_t)s0 + i * 8) * 1024, sKd + i * 512);
    __syncthreads();

    f32x4 accs[8];
    #pragma unroll
    for (int si = 0; si < 8; ++si){
      f32x4 a = {};
      #pragma unroll
      for (int dt = 0; dt < 2; ++dt){
        bf16x8 kf = *(const bf16x8*)&sK[(si * 16 + lr) * 64 + ((dt * 4 + lg) ^ (lr & 7)) * 8];
        a = __builtin_amdgcn_mfma_f32_16x16x32_bf16(qf[dt], kf, a, 0, 0, 0);
      }
      accs[si] = a;
    }

    #pragma unroll
    for (int j = 0; j < 4; ++j){
      unsigned wb[4];
      if (HAS_BIAS){
        #pragma unroll
        for (int sp = 0; sp < 4; ++sp) wb[sp] = bitrow[j][(s0 >> 5) + sp];
      }
      float vals[8];
      #pragma unroll
      for (int si = 0; si < 8; ++si){
        float v = accs[si][j] * 0.125f;
        if (HAS_BIAS && ((wb[si >> 1] >> ((si & 1) * 16 + lr)) & 1u)) v = -1e30f;
        vals[si] = v;
      }
      float mt = vals[0];
      #pragma unroll
      for (int si = 1; si < 8; ++si) mt = fmaxf(mt, vals[si]);
      const float mn = fmaxf(mrow[j], mt);
      float ssum = 0.f;
      #pragma unroll
      for (int si = 0; si < 8; ++si) ssum += __expf(vals[si] - mn);
      lrow[j] = lrow[j] * __expf(mrow[j] - mn) + ssum;
      mrow[j] = mn;
    }
  }

  // merge (m,l) across the 16 lr lanes
  #pragma unroll
  for (int j = 0; j < 4; ++j){
    #pragma unroll
    for (int d = 1; d < 16; d <<= 1){
      float mo = __shfl_xor(mrow[j], d);
      float lo = __shfl_xor(lrow[j], d);
      float mn = fmaxf(mrow[j], mo);
      lrow[j] = lrow[j] * __expf(mrow[j] - mn) + lo * __expf(mo - mn);
      mrow[j] = mn;
    }
  }
  float rinv[4];
  #pragma unroll
  for (int j = 0; j < 4; ++j) rinv[j] = 1.0f / lrow[j];

  // ---------------- Phase 2: aw + PV ----------------
  f32x4 acco[4] = {};
  for (int tt = 0; tt < NT; ++tt){
    const int s0 = tt * 128;
    __syncthreads();
    #pragma unroll
    for (int i = 0; i < 4; ++i)
      g2l16(Ksrc + ((size_t)s0 + i * 8) * 1024, sKd + i * 512);
    #pragma unroll
    for (int i = 0; i < 4; ++i){
      const int dd = w * 16 + i * 4 + (lane >> 4);
      const int cg = (lane & 15) ^ ((i * 4 + (lane >> 4)) & 15);
      g2l16(Vsrc + (size_t)dd * SK + s0 + cg * 8, sVd + i * 512);
    }
    __syncthreads();

    f32x4 accs[8];
    #pragma unroll
    for (int si = 0; si < 8; ++si){
      f32x4 a = {};
      #pragma unroll
      for (int dt = 0; dt < 2; ++dt){
        bf16x8 kf = *(const bf16x8*)&sK[(si * 16 + lr) * 64 + ((dt * 4 + lg) ^ (lr & 7)) * 8];
        a = __builtin_amdgcn_mfma_f32_16x16x32_bf16(qf[dt], kf, a, 0, 0, 0);
      }
      accs[si] = a;
    }

    #pragma unroll
    for (int j = 0; j < 4; ++j){
      unsigned wb[4];
      if (HAS_BIAS){
        #pragma unroll
        for (int sp = 0; sp < 4; ++sp) wb[sp] = bitrow[j][(s0 >> 5) + sp];
      }
      const int qq = lg * 4 + j;
      float* awrow = (MODE != 2) ?
          aw + (((size_t)(b * 16 + h)) * 512 + qw + qq) * SK + s0 + lr : nullptr;
      #pragma unroll
      for (int si = 0; si < 8; ++si){
        float v = accs[si][j] * 0.125f;
        if (HAS_BIAS && ((wb[si >> 1] >> ((si & 1) * 16 + lr)) & 1u)) v = -1e30f;
        const float p = __expf(v - mrow[j]) * rinv[j];
        if (MODE != 2) awrow[si * 16] = p;
        sPw[qq * 128 + ((si * 2 + (lr >> 3)) ^ qq) * 8 + (lr & 7)] = f2bf(p);
      }
    }

    // PV (same-wave LDS write->read; compiler inserts lgkmcnt)
    #pragma unroll
    for (int kt = 0; kt < 4; ++kt){
      bf16x8 pa = *(const bf16x8*)&sPw[lr * 128 + ((kt * 4 + lg) ^ lr) * 8];
      #pragma unroll
      for (int ni = 0; ni < 4; ++ni){
        bf16x8 vf = *(const bf16x8*)&sV[(ni * 16 + lr) * 128 + ((kt * 4 + lg) ^ lr) * 8];
        acco[ni] = __builtin_amdgcn_mfma_f32_16x16x32_bf16(pa, vf, acco[ni], 0, 0, 0);
      }
    }
  }

  // epilogue: combine into scores / concat
  #pragma unroll
  for (int ni = 0; ni < 4; ++ni)
    #pragma unroll
    for (int j = 0; j < 4; ++j){
      const size_t addr = ((size_t)(b * 512 + qw + lg * 4 + j)) * 1024 + h * 64 + ni * 16 + lr;
      const float v = acco[ni][j];
      if (MODE == 0)      scores[addr] = v;
      else if (MODE == 1) scores[addr] += 0.5f * v;
      else                concat[addr] = f2bf(scores[addr] + 0.5f * v);
    }
}

// ---------------------------------------------------------------------------
extern "C" void kernel_launch(void* const* d_in, const int* in_sizes, int n_in,
                              void* d_out, int out_size, void* d_ws, size_t ws_size,
                              hipStream_t stream){
  const float* q    = (const float*)d_in[0];
  const float* k_e  = (const float*)d_in[1];
  const float* v_e  = (const float*)d_in[2];
  const float* k_i  = (const float*)d_in[3];
  const float* v_i  = (const float*)d_in[4];
  const float* k_ei = (const float*)d_in[5];
  const float* v_ei = (const float*)d_in[6];
  const int* mask_e  = (const int*)d_in[7];
  const int* mask_ei = (const int*)d_in[8];
  const int* pad_e   = (const int*)d_in[9];
  const int* pad_ei  = (const int*)d_in[10];
  const float* Wq   = (const float*)d_in[11]; const float* bq   = (const float*)d_in[12];
  const float* Wke  = (const float*)d_in[13]; const float* bke  = (const float*)d_in[14];
  const float* Wve  = (const float*)d_in[15]; const float* bve  = (const float*)d_in[16];
  const float* Wki  = (const float*)d_in[17]; const float* bki  = (const float*)d_in[18];
  const float* Wvi  = (const float*)d_in[19]; const float* bvi  = (const float*)d_in[20];
  const float* Wkei = (const float*)d_in[21]; const float* bkei = (const float*)d_in[22];
  const float* Wvei = (const float*)d_in[23]; const float* bvei = (const float*)d_in[24];
  const float* Wout = (const float*)d_in[25]; const float* bout = (const float*)d_in[26];

  char* ws = (char*)d_ws;
  short* PW     = (short*)(ws);                 // 16 MB: 8 packed weights (bf16)
  short* Abf    = (short*)(ws + 16777216);      // 24 MB: bf16 staging; later bitmasks
  short* Qp     = (short*)(ws + 41943040);      // 8192x1024 bf16
  short* Kep    = (short*)(ws + 58720256);      // 8192x1024 bf16
  short* Kip    = (short*)(ws + 75497472);      // 4096x1024 bf16
  short* Keip   = (short*)(ws + 83886080);      // 12288x1024 bf16
  short* Vte    = (short*)(ws + 109051904);     // (16,16,64,512) bf16
  short* Vti    = (short*)(ws + 125829120);     // (16,16,64,256) bf16
  short* Vtei   = (short*)(ws + 134217728);     // (16,16,64,768) bf16
  float* scores = (float*)(ws + 159383552);     // 8192x1024 f32
  short* concat = (short*)(ws + 192937984);     // 8192x1024 bf16  (ends 209715200)

  unsigned* bits_e  = (unsigned*)(ws + 16777216);            // 2 MB (in Abf, after cvt use)
  unsigned* bits_ei = (unsigned*)(ws + 16777216 + 2097152);  // 3 MB

  float* out0 = (float*)d_out;
  float* aw_e = out0 + 8388608;
  float* aw_i = out0 + 75497472;

  const float* Wl[8] = {Wq, Wke, Wve, Wki, Wvi, Wkei, Wvei, Wout};
  for (int m = 0; m < 8; ++m)
    pack_w<<<256, 256, 0, stream>>>(Wl[m], PW + (size_t)m * 1048576);

  // q
  cvt_bf16<<<4096, 256, 0, stream>>>(q, Abf, 1048576);
  gemm128<0><<<dim3(64, 8), 256, 0, stream>>>(Abf, PW + 0 * 1048576, bq, Qp, 512);
  // k_e
  cvt_bf16<<<4096, 256, 0, stream>>>(k_e, Abf, 1048576);
  gemm128<0><<<dim3(64, 8), 256, 0, stream>>>(Abf, PW + 1 * 1048576, bke, Kep, 512);
  // v_e
  cvt_bf16<<<4096, 256, 0, stream>>>(v_e, Abf, 1048576);
  gemm128<1><<<dim3(64, 8), 256, 0, stream>>>(Abf, PW + 2 * 1048576, bve, Vte, 512);
  // k_i
  cvt_bf16<<<2048, 256, 0, stream>>>(k_i, Abf, 524288);
  gemm128<0><<<dim3(32, 8), 256, 0, stream>>>(Abf, PW + 3 * 1048576, bki, Kip, 256);
  // v_i
  cvt_bf16<<<2048, 256, 0, stream>>>(v_i, Abf, 524288);
  gemm128<1><<<dim3(32, 8), 256, 0, stream>>>(Abf, PW + 4 * 1048576, bvi, Vti, 256);
  // k_ei
  cvt_bf16<<<6144, 256, 0, stream>>>(k_ei, Abf, 1572864);
  gemm128<0><<<dim3(96, 8), 256, 0, stream>>>(Abf, PW + 5 * 1048576, bkei, Keip, 768);
  // v_ei
  cvt_bf16<<<6144, 256, 0, stream>>>(v_ei, Abf, 1572864);
  gemm128<1><<<dim3(96, 8), 256, 0, stream>>>(Abf, PW + 6 * 1048576, bvei, Vtei, 768);

  // bitmasks (Abf region is free now)
  make_bits<<<dim3(2, 8192), 256, 0, stream>>>(mask_e,  pad_e,  bits_e,  512);
  make_bits<<<dim3(3, 8192), 256, 0, stream>>>(mask_ei, pad_ei, bits_ei, 768);

  attn2<512, true , 0><<<2048, 256, 0, stream>>>(Qp, Kep,  Vte,  bits_e,  aw_e, scores, nullptr);
  attn2<256, false, 1><<<2048, 256, 0, stream>>>(Qp, Kip,  Vti,  nullptr, aw_i, scores, nullptr);
  attn2<768, true , 2><<<2048, 256, 0, stream>>>(Qp, Keip, Vtei, bits_ei, nullptr, scores, concat);

  gemm128<2><<<dim3(64, 8), 256, 0, stream>>>(concat, PW + 7 * 1048576, bout, out0, 512);
}